// Round 3
// baseline (841.403 us; speedup 1.0000x reference)
//
#include <hip/hip_runtime.h>
#include <cstdint>

typedef unsigned long long u64;
typedef unsigned int u32;

// ---------------------------------------------------------------------------
// SNN: 64-step scan over 3 spike-gated linear layers, all internal math f64.
// Spikes are kept as DENSE f64 rows S[i][0..63] in {0.0, 1.0} so the gemm
// inner loop is select-free: per (i,t) exactly one v_fma_f64 whose
// multiplicand comes from an SGPR pair (uniform s_load of the S row).
// Round-2 lesson: the s_and/s_cselect per t put 2 SALU ops per FMA on the
// one-per-CU scalar ALU -> scalar-bound at 32% VALUBusy. Dense-S removes it.
// ---------------------------------------------------------------------------

__global__ __launch_bounds__(256) void k_input(const float* __restrict__ img,
                                               float* __restrict__ out0, // 65 x n
                                               double* __restrict__ S0,  // n x 64
                                               int n)
{
    int i = blockIdx.x * 256 + threadIdx.x;
    if (i >= n) return;
    double m = 0.0;
    double x = (double)img[i];
#pragma unroll
    for (int t = 0; t < 64; ++t) {
        m += x;
        bool fire = (m >= 1.0);
        if (fire) m -= 1.0;          // input layer: no decay
        out0[(size_t)t * n + i] = fire ? 1.0f : 0.0f;
        S0[((size_t)i << 6) + t]  = fire ? 1.0 : 0.0;
    }
    out0[(size_t)64 * n + i] = 0.0f; // pad_tail: last row zero
}

// Spike-gated GEMM partials.
// Grid: (n_out/256, nchunks, 2). Block: 256 (one output column j per thread).
// h = blockIdx.z picks the 32-timestep half. S row slice is wave-uniform ->
// scalar loads; inner body is 1 cvt + 32 v_fma_f64 per i.
__global__ __launch_bounds__(256) void k_gemm(const float* __restrict__ W,
                                              const double* __restrict__ S, // n_in x 64
                                              double* __restrict__ P,
                                              int n_in, int n_out, int i_per_chunk)
{
    int j = blockIdx.x * 256 + threadIdx.x;
    int h = blockIdx.z;                       // 0/1 timestep half (uniform)
    int c = blockIdx.y;
    int i0 = c * i_per_chunk;
    int i1 = i0 + i_per_chunk;
    if (i1 > n_in) i1 = n_in;

    double acc[32];
#pragma unroll
    for (int t = 0; t < 32; ++t) acc[t] = 0.0;

    const float* wp = W + (size_t)i0 * n_out + j;
    float wf = (i0 < i1) ? *wp : 0.0f;        // prefetched current w
    for (int i = i0; i < i1; ++i) {
        float wn = (i + 1 < i1) ? wp[n_out] : 0.0f;   // prefetch next
        const double* srow = S + ((size_t)i << 6) + (h << 5); // uniform addr
        double wd = (double)wf;
#pragma unroll
        for (int t = 0; t < 32; ++t)
            acc[t] = fma(srow[t], wd, acc[t]);        // s[t] in SGPR pair
        wf = wn;
        wp += n_out;
    }

    double* p = P + ((size_t)(c * 2 + h) * 32) * n_out + j;
#pragma unroll
    for (int t = 0; t < 32; ++t) p[(size_t)t * n_out] = acc[t];
}

// U[t][j] = sum over chunks c of P[(c*2 + t/32)][t%32][j]  (fixed order: deterministic)
__global__ __launch_bounds__(256) void k_reduceU(const double* __restrict__ P,
                                                 double* __restrict__ U,
                                                 int nchunks, int n_out)
{
    int gid = blockIdx.x * 256 + threadIdx.x;
    int total = 64 * n_out;
    if (gid >= total) return;
    int t = gid / n_out;
    int j = gid - t * n_out;
    int h = t >> 5, tl = t & 31;
    double s = 0.0;
    for (int c = 0; c < nchunks; ++c)
        s += P[((size_t)(c * 2 + h) * 32 + tl) * n_out + j];
    U[gid] = s;
}

// Per-neuron membrane scan; also emits the next layer's dense S rows.
// shift=1 => this layer consumes the previous step's spikes (read U[t-1]).
__global__ __launch_bounds__(256) void k_scan(const double* __restrict__ U,
                                              float* __restrict__ outS, // 65 x n_out (pad_head)
                                              double* __restrict__ Sd,  // n_out x 64, may be null
                                              int n_out, int shift)
{
    int j = blockIdx.x * 256 + threadIdx.x;
    if (j >= n_out) return;
    double m = 0.0;
    outS[j] = 0.0f;                           // row 0 zero (pad_head)
    for (int t = 0; t < 64; ++t) {
        int s = t - shift;
        double u = (s >= 0) ? U[(size_t)s * n_out + j] : 0.0;
        m += u;
        bool fire = (m >= 1.0);
        m = fire ? (m - 1.0) : (m * 0.5);
        outS[(size_t)(t + 1) * n_out + j] = fire ? 1.0f : 0.0f;
        if (Sd) Sd[((size_t)j << 6) + t] = fire ? 1.0 : 0.0;
    }
}

extern "C" void kernel_launch(void* const* d_in, const int* in_sizes, int n_in_cnt,
                              void* d_out, int out_size, void* d_ws, size_t ws_size,
                              hipStream_t stream)
{
    const float* img = (const float*)d_in[0];
    const float* w1  = (const float*)d_in[1];
    const float* w2  = (const float*)d_in[2];
    const float* w3  = (const float*)d_in[3];

    const int N0 = 16384, N1 = 4096, N2 = 4096, N3 = 1024;

    float* out0 = (float*)d_out;
    float* out1 = out0 + (size_t)65 * N0;
    float* out2 = out1 + (size_t)65 * N1;
    float* out3 = out2 + (size_t)65 * N2;

    // workspace layout (all offsets 256B-aligned)
    char* ws = (char*)d_ws;
    const size_t MB = 1024 * 1024;
    double* S0 = (double*)(ws);               // 16384*64*8 = 8 MiB
    double* S1 = (double*)(ws + 8 * MB);      //  4096*64*8 = 2 MiB
    double* S2 = (double*)(ws + 10 * MB);     //  2 MiB
    double* U  = (double*)(ws + 12 * MB);     // 64*4096*8 = 2 MiB
    double* P  = (double*)(ws + 14 * MB);

    size_t fixed = 14 * MB;
    size_t pbudget = (ws_size > fixed) ? (ws_size - fixed) : 0;

    // P bytes per chunk = 2 halves x 32 t x n_out x 8B = 512*n_out
    auto clampi = [](long v, int lo, int hi) { int x = (int)v; if (x < lo) x = lo; if (x > hi) x = hi; return x; };
    int C1 = clampi((long)(pbudget / (512ull * N1)), 1, 32);
    int C2 = clampi((long)(pbudget / (512ull * N2)), 1, 24);
    int C3 = clampi((long)(pbudget / (512ull * N3)), 1, 64);

    // layer 0 (input): spikes + dense S0
    k_input<<<N0 / 256, 256, 0, stream>>>(img, out0, S0, N0);

    // layer 1: U1 = S0 @ W1 (same-step spikes)
    k_gemm<<<dim3(N1 / 256, C1, 2), 256, 0, stream>>>(w1, S0, P, N0, N1, (N0 + C1 - 1) / C1);
    k_reduceU<<<(64 * N1) / 256, 256, 0, stream>>>(P, U, C1, N1);
    k_scan<<<N1 / 256, 256, 0, stream>>>(U, out1, S1, N1, 0);

    // layer 2: uses previous-step s1
    k_gemm<<<dim3(N2 / 256, C2, 2), 256, 0, stream>>>(w2, S1, P, N1, N2, (N1 + C2 - 1) / C2);
    k_reduceU<<<(64 * N2) / 256, 256, 0, stream>>>(P, U, C2, N2);
    k_scan<<<N2 / 256, 256, 0, stream>>>(U, out2, S2, N2, 1);

    // layer 3: uses previous-step s2
    k_gemm<<<dim3(N3 / 256, C3, 2), 256, 0, stream>>>(w3, S2, P, N1, N3, (N1 + C3 - 1) / C3);
    k_reduceU<<<(64 * N3) / 256, 256, 0, stream>>>(P, U, C3, N3);
    k_scan<<<N3 / 256, 256, 0, stream>>>(U, out3, (double*)nullptr, N3, 1);
}

// Round 5
// 528.859 us; speedup vs baseline: 1.5910x; 1.5910x over previous
//
#include <hip/hip_runtime.h>
#include <cstdint>

typedef double d4 __attribute__((ext_vector_type(4)));

// ---------------------------------------------------------------------------
// SNN: 64-step scan over 3 spike-gated linear layers, all internal math f64.
// GEMM uses v_mfma_f64_16x16x4_f64. Round-4 lesson: the f64 MFMA fragment
// layout is NOT the m89-verified bf16 layout. Fix: k_probe measures the
// layout on-device (2 MFMAs with identity-like operands) and writes LUTs;
// spike writers / weight loads / D stores are LUT-driven.
//
// LUT layout (int32):
//  [0..63]    lutAinv[m*4+k] -> lane that holds arg0 free-index m, summed k
//  [64..127]  kB[lane]  summed-index (i) offset for arg1 (weight) load
//  [128..191] nB[lane]  free-index (j) offset for arg1 load
//  [192..447] rowD[r*64+lane] : D row within 16x16 tile
//  [448..703] colD[r*64+lane] : D col within 16x16 tile
// ---------------------------------------------------------------------------

__global__ __launch_bounds__(64) void k_probe(int* __restrict__ lut)
{
    int l = threadIdx.x;
    d4 z = {0.0, 0.0, 0.0, 0.0};
    // D = arg0_matrix . arg1_matrix (16x4 . 4x16), 1 f64/lane per operand.
    d4 d1 = __builtin_amdgcn_mfma_f64_16x16x4f64(1.0, (double)l, z, 0, 0, 0);
    d4 d2 = __builtin_amdgcn_mfma_f64_16x16x4f64((double)l, 1.0, z, 0, 0, 0);
    int amode = 0, bmode = 0;
    int rw[4], cl[4];
#pragma unroll
    for (int r = 0; r < 4; ++r) {
        // col fingerprint: lanes sharing arg1 free-index n sum their ids.
        // {n,n+16,n+32,n+48} -> 4n+96 (==0 mod 4); {4n..4n+3} -> 16n+6 (==2 mod 4)
        int v1 = (int)(d1[r] + 0.5);
        if ((v1 & 3) == 0) { cl[r] = (v1 - 96) >> 2; bmode = 0; }
        else               { cl[r] = (v1 - 6) >> 4;  bmode = 1; }
        int v2 = (int)(d2[r] + 0.5);
        if ((v2 & 3) == 0) { rw[r] = (v2 - 96) >> 2; amode = 0; }
        else               { rw[r] = (v2 - 6) >> 4;  amode = 1; }
    }
    {   // inverse map (m,k) -> lane for the spike-fragment writers
        int m = l >> 2, k = l & 3;
        lut[l] = (amode == 0) ? (m + (k << 4)) : ((m << 2) + k);
    }
    lut[64 + l]  = (bmode == 0) ? (l >> 4) : (l & 3);
    lut[128 + l] = (bmode == 0) ? (l & 15) : (l >> 2);
#pragma unroll
    for (int r = 0; r < 4; ++r) {
        lut[192 + (r << 6) + l] = rw[r];
        lut[448 + (r << 6) + l] = cl[r];
    }
}

// SA block layout: SA[i>>2][tt=t>>4][ lane = lutAinv[(t&15)*4 + (i&3)] ]
__global__ __launch_bounds__(256) void k_input(const float* __restrict__ img,
                                               float* __restrict__ out0, // 65 x n
                                               double* __restrict__ SA0,
                                               const int* __restrict__ lut, int n)
{
    int i = blockIdx.x * 256 + threadIdx.x;
    if (i >= n) return;
    int lanes[16];
#pragma unroll
    for (int m = 0; m < 16; ++m) lanes[m] = lut[(m << 2) + (i & 3)];
    double* base = SA0 + ((size_t)(i >> 2) << 8);
    double m = 0.0;
    double x = (double)img[i];
#pragma unroll
    for (int t = 0; t < 64; ++t) {
        m += x;
        bool fire = (m >= 1.0);
        if (fire) m -= 1.0;          // input layer: no decay
        out0[(size_t)t * n + i] = fire ? 1.0f : 0.0f;
        base[((t >> 4) << 6) + lanes[t & 15]] = fire ? 1.0 : 0.0;
    }
    out0[(size_t)64 * n + i] = 0.0f; // pad_tail: last row zero
}

// MFMA spike-gated GEMM partials: P[c][t][j] = sum_{i in chunk c} S[t][i]*W[i][j]
// Grid: (n_out/128, nchunks). Block 256 = 4 waves; each wave owns 32 j x 64 t.
__global__ __launch_bounds__(256) void k_gemm(const float* __restrict__ W,
                                              const double* __restrict__ SA,
                                              double* __restrict__ P,
                                              const int* __restrict__ lut,
                                              int n_in, int n_out, int i_per_chunk)
{
    const int lane = threadIdx.x & 63;
    const int wv   = threadIdx.x >> 6;
    const int j0   = blockIdx.x * 128 + wv * 32;
    const int c    = blockIdx.y;

    const int kB = lut[64 + lane];
    const int nB = lut[128 + lane];
    int rw[4], cl[4];
#pragma unroll
    for (int r = 0; r < 4; ++r) {
        rw[r] = lut[192 + (r << 6) + lane];
        cl[r] = lut[448 + (r << 6) + lane];
    }

    int i0 = c * i_per_chunk;
    int i1 = i0 + i_per_chunk; if (i1 > n_in) i1 = n_in;

    d4 acc[2][4];
#pragma unroll
    for (int jt = 0; jt < 2; ++jt)
#pragma unroll
        for (int tt = 0; tt < 4; ++tt) acc[jt][tt] = (d4){0.0, 0.0, 0.0, 0.0};

    const float*  wp = W  + (size_t)(i0 + kB) * n_out + j0 + nB;
    const double* ap = SA + ((size_t)(i0 >> 2) << 8) + lane;

    float  b0f = 0.f, b1f = 0.f;
    double a0 = 0., a1 = 0., a2 = 0., a3 = 0.;
    if (i0 < i1) {
        b0f = wp[0]; b1f = wp[16];
        a0 = ap[0]; a1 = ap[64]; a2 = ap[128]; a3 = ap[192];
    }
    for (int i = i0; i < i1; i += 4) {
        float  nb0 = 0.f, nb1 = 0.f;
        double na0 = 0., na1 = 0., na2 = 0., na3 = 0.;
        wp += (size_t)4 * n_out; ap += 256;
        if (i + 4 < i1) {
            nb0 = wp[0]; nb1 = wp[16];
            na0 = ap[0]; na1 = ap[64]; na2 = ap[128]; na3 = ap[192];
        }
        double b0 = (double)b0f, b1 = (double)b1f;
        acc[0][0] = __builtin_amdgcn_mfma_f64_16x16x4f64(a0, b0, acc[0][0], 0, 0, 0);
        acc[0][1] = __builtin_amdgcn_mfma_f64_16x16x4f64(a1, b0, acc[0][1], 0, 0, 0);
        acc[0][2] = __builtin_amdgcn_mfma_f64_16x16x4f64(a2, b0, acc[0][2], 0, 0, 0);
        acc[0][3] = __builtin_amdgcn_mfma_f64_16x16x4f64(a3, b0, acc[0][3], 0, 0, 0);
        acc[1][0] = __builtin_amdgcn_mfma_f64_16x16x4f64(a0, b1, acc[1][0], 0, 0, 0);
        acc[1][1] = __builtin_amdgcn_mfma_f64_16x16x4f64(a1, b1, acc[1][1], 0, 0, 0);
        acc[1][2] = __builtin_amdgcn_mfma_f64_16x16x4f64(a2, b1, acc[1][2], 0, 0, 0);
        acc[1][3] = __builtin_amdgcn_mfma_f64_16x16x4f64(a3, b1, acc[1][3], 0, 0, 0);
        b0f = nb0; b1f = nb1; a0 = na0; a1 = na1; a2 = na2; a3 = na3;
    }

    // D element (lane, r) sits at (row rw[r], col cl[r]) of its 16x16 tile.
    double* pc = P + (size_t)c * 64 * n_out;
#pragma unroll
    for (int jt = 0; jt < 2; ++jt)
#pragma unroll
        for (int tt = 0; tt < 4; ++tt)
#pragma unroll
            for (int r = 0; r < 4; ++r)
                pc[(size_t)(tt * 16 + rw[r]) * n_out + (j0 + jt * 16 + cl[r])] = acc[jt][tt][r];
}

// U[t][j] = sum over chunks c of P[c][t][j]  (fixed order: deterministic)
__global__ __launch_bounds__(256) void k_reduceU(const double* __restrict__ P,
                                                 double* __restrict__ U,
                                                 int nchunks, int n_out)
{
    int gid = blockIdx.x * 256 + threadIdx.x;
    int total = 64 * n_out;
    if (gid >= total) return;
    int t = gid / n_out;
    int j = gid - t * n_out;
    double s = 0.0;
    for (int c = 0; c < nchunks; ++c)
        s += P[((size_t)c * 64 + t) * n_out + j];
    U[gid] = s;
}

// Per-neuron membrane scan; emits next layer's spike fragments via the LUT.
// shift=1 => this layer consumes the previous step's spikes (read U[t-1]).
__global__ __launch_bounds__(256) void k_scan(const double* __restrict__ U,
                                              float* __restrict__ outS, // 65 x n_out (pad_head)
                                              double* __restrict__ SAn, // may be null
                                              const int* __restrict__ lut,
                                              int n_out, int shift)
{
    int j = blockIdx.x * 256 + threadIdx.x;
    if (j >= n_out) return;
    int lanes[16];
#pragma unroll
    for (int m = 0; m < 16; ++m) lanes[m] = lut[(m << 2) + (j & 3)];
    double* base = SAn ? (SAn + ((size_t)(j >> 2) << 8)) : (double*)nullptr;
    double m = 0.0;
    outS[j] = 0.0f;                           // row 0 zero (pad_head)
#pragma unroll
    for (int t = 0; t < 64; ++t) {
        int s = t - shift;
        double u = (s >= 0) ? U[(size_t)s * n_out + j] : 0.0;
        m += u;
        bool fire = (m >= 1.0);
        m = fire ? (m - 1.0) : (m * 0.5);
        outS[(size_t)(t + 1) * n_out + j] = fire ? 1.0f : 0.0f;
        if (base) base[((t >> 4) << 6) + lanes[t & 15]] = fire ? 1.0 : 0.0;
    }
}

extern "C" void kernel_launch(void* const* d_in, const int* in_sizes, int n_in_cnt,
                              void* d_out, int out_size, void* d_ws, size_t ws_size,
                              hipStream_t stream)
{
    const float* img = (const float*)d_in[0];
    const float* w1  = (const float*)d_in[1];
    const float* w2  = (const float*)d_in[2];
    const float* w3  = (const float*)d_in[3];

    const int N0 = 16384, N1 = 4096, N2 = 4096, N3 = 1024;

    float* out0 = (float*)d_out;
    float* out1 = out0 + (size_t)65 * N0;
    float* out2 = out1 + (size_t)65 * N1;
    float* out3 = out2 + (size_t)65 * N2;

    // workspace layout
    char* ws = (char*)d_ws;
    const size_t MB = 1024 * 1024;
    double* SA0 = (double*)(ws);               // 16384*64*8 = 8 MiB
    double* SA1 = (double*)(ws + 8 * MB);      //  2 MiB
    double* SA2 = (double*)(ws + 10 * MB);     //  2 MiB
    double* U   = (double*)(ws + 12 * MB);     //  2 MiB
    int*    lut = (int*)   (ws + 14 * MB);     //  2816 B (704 ints)
    double* P   = (double*)(ws + 14 * MB + 4096);

    size_t fixed = 14 * MB + 4096;
    size_t pbudget = (ws_size > fixed) ? (ws_size - fixed) : 0;

    // P bytes per chunk = 64 t x n_out x 8B = 512*n_out
    auto clampi = [](long v, int lo, int hi) { int x = (int)v; if (x < lo) x = lo; if (x > hi) x = hi; return x; };
    int C1 = clampi((long)(pbudget / (512ull * N1)), 1, 32);
    int C2 = clampi((long)(pbudget / (512ull * N2)), 1, 24);
    int C3 = clampi((long)(pbudget / (512ull * N3)), 1, 32);

    auto ipc4 = [](int n_in, int C) { return (((n_in + C - 1) / C) + 3) & ~3; };

    // measure the f64 MFMA fragment layout (writes lut; same stream -> ordered)
    k_probe<<<1, 64, 0, stream>>>(lut);

    // layer 0 (input): spikes + fragment-layout S0
    k_input<<<N0 / 256, 256, 0, stream>>>(img, out0, SA0, lut, N0);

    // layer 1: U1 = S0 @ W1 (same-step spikes)
    k_gemm<<<dim3(N1 / 128, C1), 256, 0, stream>>>(w1, SA0, P, lut, N0, N1, ipc4(N0, C1));
    k_reduceU<<<(64 * N1) / 256, 256, 0, stream>>>(P, U, C1, N1);
    k_scan<<<N1 / 256, 256, 0, stream>>>(U, out1, SA1, lut, N1, 0);

    // layer 2: uses previous-step s1
    k_gemm<<<dim3(N2 / 128, C2), 256, 0, stream>>>(w2, SA1, P, lut, N1, N2, ipc4(N1, C2));
    k_reduceU<<<(64 * N2) / 256, 256, 0, stream>>>(P, U, C2, N2);
    k_scan<<<N2 / 256, 256, 0, stream>>>(U, out2, SA2, lut, N2, 1);

    // layer 3: uses previous-step s2
    k_gemm<<<dim3(N3 / 128, C3), 256, 0, stream>>>(w3, SA2, P, lut, N1, N3, ipc4(N1, C3));
    k_reduceU<<<(64 * N3) / 256, 256, 0, stream>>>(P, U, C3, N3);
    k_scan<<<N3 / 256, 256, 0, stream>>>(U, out3, (double*)nullptr, lut, N3, 1);
}

// Round 6
// 353.351 us; speedup vs baseline: 2.3812x; 1.4967x over previous
//
#include <hip/hip_runtime.h>
#include <cstdint>

typedef double d4 __attribute__((ext_vector_type(4)));

// ---------------------------------------------------------------------------
// SNN: 64-step scan over 3 spike-gated linear layers, all internal math f64.
// GEMM uses v_mfma_f64_16x16x4_f64 with an on-device-probed fragment layout
// (round-4 lesson: f64 MFMA layout differs from the bf16 family; k_probe
// measures it and writes LUTs consumed by all producers/consumers).
// Round-5 lesson: 1-deep prefetch covers ~512 cyc < ~900 cyc HBM latency ->
// MfmaUtil stuck at 35%. Fix: depth-2 pipeline via THREE explicit register
// sets (no rotation movs); loads land ~1024 compute-cycles before use.
// ---------------------------------------------------------------------------

__global__ __launch_bounds__(64) void k_probe(int* __restrict__ lut)
{
    int l = threadIdx.x;
    d4 z = {0.0, 0.0, 0.0, 0.0};
    d4 d1 = __builtin_amdgcn_mfma_f64_16x16x4f64(1.0, (double)l, z, 0, 0, 0);
    d4 d2 = __builtin_amdgcn_mfma_f64_16x16x4f64((double)l, 1.0, z, 0, 0, 0);
    int amode = 0, bmode = 0;
    int rw[4], cl[4];
#pragma unroll
    for (int r = 0; r < 4; ++r) {
        int v1 = (int)(d1[r] + 0.5);
        if ((v1 & 3) == 0) { cl[r] = (v1 - 96) >> 2; bmode = 0; }
        else               { cl[r] = (v1 - 6) >> 4;  bmode = 1; }
        int v2 = (int)(d2[r] + 0.5);
        if ((v2 & 3) == 0) { rw[r] = (v2 - 96) >> 2; amode = 0; }
        else               { rw[r] = (v2 - 6) >> 4;  amode = 1; }
    }
    {
        int m = l >> 2, k = l & 3;
        lut[l] = (amode == 0) ? (m + (k << 4)) : ((m << 2) + k);
    }
    lut[64 + l]  = (bmode == 0) ? (l >> 4) : (l & 3);
    lut[128 + l] = (bmode == 0) ? (l & 15) : (l >> 2);
#pragma unroll
    for (int r = 0; r < 4; ++r) {
        lut[192 + (r << 6) + l] = rw[r];
        lut[448 + (r << 6) + l] = cl[r];
    }
}

// SA block layout: SA[i>>2][tt=t>>4][ lane = lutAinv[(t&15)*4 + (i&3)] ]
__global__ __launch_bounds__(256) void k_input(const float* __restrict__ img,
                                               float* __restrict__ out0, // 65 x n
                                               double* __restrict__ SA0,
                                               const int* __restrict__ lut, int n)
{
    int i = blockIdx.x * 256 + threadIdx.x;
    if (i >= n) return;
    int lanes[16];
#pragma unroll
    for (int m = 0; m < 16; ++m) lanes[m] = lut[(m << 2) + (i & 3)];
    double* base = SA0 + ((size_t)(i >> 2) << 8);
    double m = 0.0;
    double x = (double)img[i];
#pragma unroll
    for (int t = 0; t < 64; ++t) {
        m += x;
        bool fire = (m >= 1.0);
        if (fire) m -= 1.0;          // input layer: no decay
        out0[(size_t)t * n + i] = fire ? 1.0f : 0.0f;
        base[((t >> 4) << 6) + lanes[t & 15]] = fire ? 1.0 : 0.0;
    }
    out0[(size_t)64 * n + i] = 0.0f; // pad_tail: last row zero
}

// MFMA spike-gated GEMM partials: P[c][t][j] = sum_{i in chunk c} S[t][i]*W[i][j]
// Grid: (n_out/128, nchunks). Block 256 = 4 waves; each wave owns 32 j x 64 t.
// Depth-2 software pipeline, 3 register sets.
__global__ __launch_bounds__(256, 3) void k_gemm(const float* __restrict__ W,
                                                 const double* __restrict__ SA,
                                                 double* __restrict__ P,
                                                 const int* __restrict__ lut,
                                                 int n_in, int n_out, int i_per_chunk)
{
    const int lane = threadIdx.x & 63;
    const int wv   = threadIdx.x >> 6;
    const int j0   = blockIdx.x * 128 + wv * 32;
    const int c    = blockIdx.y;

    const int kB = lut[64 + lane];
    const int nB = lut[128 + lane];
    int rw[4], cl[4];
#pragma unroll
    for (int r = 0; r < 4; ++r) {
        rw[r] = lut[192 + (r << 6) + lane];
        cl[r] = lut[448 + (r << 6) + lane];
    }

    int i0 = c * i_per_chunk;
    int i1 = i0 + i_per_chunk; if (i1 > n_in) i1 = n_in;
    int nsteps = (i1 > i0) ? ((i1 - i0) >> 2) : 0;   // 4 i's per step

    d4 acc[2][4];
#pragma unroll
    for (int jt = 0; jt < 2; ++jt)
#pragma unroll
        for (int tt = 0; tt < 4; ++tt) acc[jt][tt] = (d4){0.0, 0.0, 0.0, 0.0};

    const size_t wstep = (size_t)4 * n_out;          // W elems per step
    const float*  wp0 = W  + (size_t)(i0 + kB) * n_out + j0 + nB;
    const double* ap0 = SA + (((size_t)i0 >> 2) << 8) + lane;

    // three load sets, each serving steps s = k, k+3, k+6, ...
    const float*  Awp = wp0;              const double* Aap = ap0;
    const float*  Bwp = wp0 + wstep;      const double* Bap = ap0 + 256;
    const float*  Cwp = wp0 + 2 * wstep;  const double* Cap = ap0 + 512;
    double Aa0, Aa1, Aa2, Aa3; float Ab0, Ab1;
    double Ba0, Ba1, Ba2, Ba3; float Bb0, Bb1;
    double Ca0, Ca1, Ca2, Ca3; float Cb0, Cb1;

#define LOADSET(S, sidx) do {                                                  \
        if ((sidx) < nsteps) {                                                 \
            S##b0 = S##wp[0];  S##b1 = S##wp[16];                              \
            S##a0 = S##ap[0];  S##a1 = S##ap[64];                              \
            S##a2 = S##ap[128]; S##a3 = S##ap[192];                            \
        } else {                                                               \
            S##b0 = 0.f; S##b1 = 0.f;                                          \
            S##a0 = 0.0; S##a1 = 0.0; S##a2 = 0.0; S##a3 = 0.0;                \
        }                                                                      \
        S##wp += 3 * wstep; S##ap += 768;                                      \
    } while (0)

#define COMPUTESET(S) do {                                                     \
        double b0 = (double)S##b0, b1 = (double)S##b1;                         \
        acc[0][0] = __builtin_amdgcn_mfma_f64_16x16x4f64(S##a0, b0, acc[0][0], 0, 0, 0); \
        acc[1][0] = __builtin_amdgcn_mfma_f64_16x16x4f64(S##a0, b1, acc[1][0], 0, 0, 0); \
        acc[0][1] = __builtin_amdgcn_mfma_f64_16x16x4f64(S##a1, b0, acc[0][1], 0, 0, 0); \
        acc[1][1] = __builtin_amdgcn_mfma_f64_16x16x4f64(S##a1, b1, acc[1][1], 0, 0, 0); \
        acc[0][2] = __builtin_amdgcn_mfma_f64_16x16x4f64(S##a2, b0, acc[0][2], 0, 0, 0); \
        acc[1][2] = __builtin_amdgcn_mfma_f64_16x16x4f64(S##a2, b1, acc[1][2], 0, 0, 0); \
        acc[0][3] = __builtin_amdgcn_mfma_f64_16x16x4f64(S##a3, b0, acc[0][3], 0, 0, 0); \
        acc[1][3] = __builtin_amdgcn_mfma_f64_16x16x4f64(S##a3, b1, acc[1][3], 0, 0, 0); \
    } while (0)

    LOADSET(A, 0);
    LOADSET(B, 1);
    LOADSET(C, 2);

    int rounds = (nsteps + 2) / 3;
    int s = 0;
    for (int r = 0; r < rounds; ++r) {
        COMPUTESET(A); LOADSET(A, s + 3);   // consumed 2 computes from now
        COMPUTESET(B); LOADSET(B, s + 4);
        COMPUTESET(C); LOADSET(C, s + 5);
        s += 3;
    }
#undef LOADSET
#undef COMPUTESET

    // D element (lane, r) sits at (row rw[r], col cl[r]) of its 16x16 tile.
    double* pc = P + (size_t)c * 64 * n_out;
#pragma unroll
    for (int jt = 0; jt < 2; ++jt)
#pragma unroll
        for (int tt = 0; tt < 4; ++tt)
#pragma unroll
            for (int r = 0; r < 4; ++r)
                pc[(size_t)(tt * 16 + rw[r]) * n_out + (j0 + jt * 16 + cl[r])] = acc[jt][tt][r];
}

// U[t][j] = sum over chunks c of P[c][t][j]  (fixed order: deterministic)
__global__ __launch_bounds__(256) void k_reduceU(const double* __restrict__ P,
                                                 double* __restrict__ U,
                                                 int nchunks, int n_out)
{
    int gid = blockIdx.x * 256 + threadIdx.x;
    int total = 64 * n_out;
    if (gid >= total) return;
    int t = gid / n_out;
    int j = gid - t * n_out;
    double s = 0.0;
    for (int c = 0; c < nchunks; ++c)
        s += P[((size_t)c * 64 + t) * n_out + j];
    U[gid] = s;
}

// Per-neuron membrane scan; emits next layer's spike fragments via the LUT.
// shift=1 => this layer consumes the previous step's spikes (read U[t-1]).
__global__ __launch_bounds__(256) void k_scan(const double* __restrict__ U,
                                              float* __restrict__ outS, // 65 x n_out (pad_head)
                                              double* __restrict__ SAn, // may be null
                                              const int* __restrict__ lut,
                                              int n_out, int shift)
{
    int j = blockIdx.x * 256 + threadIdx.x;
    if (j >= n_out) return;
    int lanes[16];
#pragma unroll
    for (int m = 0; m < 16; ++m) lanes[m] = lut[(m << 2) + (j & 3)];
    double* base = SAn ? (SAn + ((size_t)(j >> 2) << 8)) : (double*)nullptr;
    double m = 0.0;
    outS[j] = 0.0f;                           // row 0 zero (pad_head)
#pragma unroll
    for (int t = 0; t < 64; ++t) {
        int s = t - shift;
        double u = (s >= 0) ? U[(size_t)s * n_out + j] : 0.0;
        m += u;
        bool fire = (m >= 1.0);
        m = fire ? (m - 1.0) : (m * 0.5);
        outS[(size_t)(t + 1) * n_out + j] = fire ? 1.0f : 0.0f;
        if (base) base[((t >> 4) << 6) + lanes[t & 15]] = fire ? 1.0 : 0.0;
    }
}

extern "C" void kernel_launch(void* const* d_in, const int* in_sizes, int n_in_cnt,
                              void* d_out, int out_size, void* d_ws, size_t ws_size,
                              hipStream_t stream)
{
    const float* img = (const float*)d_in[0];
    const float* w1  = (const float*)d_in[1];
    const float* w2  = (const float*)d_in[2];
    const float* w3  = (const float*)d_in[3];

    const int N0 = 16384, N1 = 4096, N2 = 4096, N3 = 1024;

    float* out0 = (float*)d_out;
    float* out1 = out0 + (size_t)65 * N0;
    float* out2 = out1 + (size_t)65 * N1;
    float* out3 = out2 + (size_t)65 * N2;

    // workspace layout
    char* ws = (char*)d_ws;
    const size_t MB = 1024 * 1024;
    double* SA0 = (double*)(ws);               // 16384*64*8 = 8 MiB
    double* SA1 = (double*)(ws + 8 * MB);      //  2 MiB
    double* SA2 = (double*)(ws + 10 * MB);     //  2 MiB
    double* U   = (double*)(ws + 12 * MB);     //  2 MiB
    int*    lut = (int*)   (ws + 14 * MB);     //  2816 B (704 ints)
    double* P   = (double*)(ws + 14 * MB + 4096);

    size_t fixed = 14 * MB + 4096;
    size_t pbudget = (ws_size > fixed) ? (ws_size - fixed) : 0;

    // P bytes per chunk = 64 t x n_out x 8B = 512*n_out
    auto clampi = [](long v, int lo, int hi) { int x = (int)v; if (x < lo) x = lo; if (x > hi) x = hi; return x; };
    int C1 = clampi((long)(pbudget / (512ull * N1)), 1, 32);
    int C2 = clampi((long)(pbudget / (512ull * N2)), 1, 24);
    int C3 = clampi((long)(pbudget / (512ull * N3)), 1, 32);

    auto ipc4 = [](int n_in, int C) { return (((n_in + C - 1) / C) + 3) & ~3; };

    // measure the f64 MFMA fragment layout (writes lut; same stream -> ordered)
    k_probe<<<1, 64, 0, stream>>>(lut);

    // layer 0 (input): spikes + fragment-layout S0
    k_input<<<N0 / 256, 256, 0, stream>>>(img, out0, SA0, lut, N0);

    // layer 1: U1 = S0 @ W1 (same-step spikes)
    k_gemm<<<dim3(N1 / 128, C1), 256, 0, stream>>>(w1, SA0, P, lut, N0, N1, ipc4(N0, C1));
    k_reduceU<<<(64 * N1) / 256, 256, 0, stream>>>(P, U, C1, N1);
    k_scan<<<N1 / 256, 256, 0, stream>>>(U, out1, SA1, lut, N1, 0);

    // layer 2: uses previous-step s1
    k_gemm<<<dim3(N2 / 128, C2), 256, 0, stream>>>(w2, SA1, P, lut, N1, N2, ipc4(N1, C2));
    k_reduceU<<<(64 * N2) / 256, 256, 0, stream>>>(P, U, C2, N2);
    k_scan<<<N2 / 256, 256, 0, stream>>>(U, out2, SA2, lut, N2, 1);

    // layer 3: uses previous-step s2
    k_gemm<<<dim3(N3 / 128, C3), 256, 0, stream>>>(w3, SA2, P, lut, N1, N3, ipc4(N1, C3));
    k_reduceU<<<(64 * N3) / 256, 256, 0, stream>>>(P, U, C3, N3);
    k_scan<<<N3 / 256, 256, 0, stream>>>(U, out3, (double*)nullptr, lut, N3, 1);
}